// Round 12
// baseline (225.381 us; speedup 1.0000x reference)
//
#include <hip/hip_runtime.h>
#include <stdint.h>

// ---------------------------------------------------------------------------
// SNN EMNIST forward: T=10, B=4096, IN=784, HID=256, NCLS=47
// R23: phase-split with BIT-PACKED A (ballot) -> tiny LDS -> hash at 4
// waves/SIMD with zero barriers.
// R22 failed because whole-A-as-bf16 = 125KB LDS -> 1 block/CU -> phase-1
// hash at 2 waves/SIMD (53% busy). Occupancy during hash is the only
// variable that has ever moved VALUBusy (2w: 53-61%, 4w: 69%, spikegen
// standalone: 82%). A as BITS is 2000 u32 = 8KB:
//  Phase 1 (barrier-free): 125 iters/lane; per iter 64 lanes hash one
//    (row,k) bit, __ballot packs 64 bits -> 2 words, lanes 0/32 ds_write.
//    Word w = row*25 + kw, bit = l&31. Same hash indices/compare as all
//    passing rounds; pad bits (k>=784) come out 0 via xv=0.
//  Phase 2 (one barrier, then barrier-free): per slab 6 B frags direct
//    global->VGPR (R21 layout, verbatim), 5 ds_read_b32 A-words (16 banks +
//    4-way broadcast = conflict-free), byte q -> bf16x8 expand (bit 2d ->
//    low bf16 of dword d, bit 2d+1 -> high; reproduces the verified frag
//    bytes), 30 MFMA in the same (nt, {hi,mid,lo}, mt) order.
// LDS 8.4KB -> 2 blocks/CU at (512,4); blocks drift (no intra-phase
// barriers): one hashes while the other gemms. I bitwise identical ->
// absmax stays 4.882812e-4. splitk (R21 [kw][n][quarter]) unchanged.
// ---------------------------------------------------------------------------

#define T_STEPS 10
#define BATCH   4096
#define IN_DIM  784
#define HID     256
#define NCLS    47
#define KWORDS  25                       // ceil(784/32)
#define KPAD    800                      // 25*32

// d_ws layout (bytes):
//   [46039040, ...)  W1{hi,mid,lo} planes: bf16, 409600 B each,
//                    layout [kw][n][quarter] (R21): elem off for (k,n) =
//                    ((kw*256+n)*4 + (k>>3)&3)*8 + (k&7),  kw = k>>5.
#define WS_W1HI_OFF 46039040u
#define WS_W1MD_OFF (46039040u + 409600u)
#define WS_W1LO_OFF (46039040u + 819200u)

typedef __attribute__((ext_vector_type(8))) short    bf16x8;
typedef __attribute__((ext_vector_type(4))) float    f32x4;
typedef __attribute__((ext_vector_type(4))) uint32_t u32x4;

__device__ __forceinline__ uint32_t rotl32(uint32_t x, uint32_t r) {
    return __builtin_amdgcn_alignbit(x, x, 32u - r);
}

// JAX threefry2x32, key=(0,42), partitionable scheme: out = o0^o1, x0=0, x1=i.
__device__ __forceinline__ uint32_t tf_hash(uint32_t lo) {
    const uint32_t ks1 = 42u;
    const uint32_t ks2 = 0x1BD11BDAu ^ 42u;
    uint32_t x0 = 0u;
    uint32_t x1 = lo + ks1;
#define TF_RND(r) { x0 += x1; x1 = rotl32(x1, r); x1 ^= x0; }
    TF_RND(13) TF_RND(15) TF_RND(26) TF_RND(6)
    x0 += ks1; x1 += ks2 + 1u;
    TF_RND(17) TF_RND(29) TF_RND(16) TF_RND(24)
    x0 += ks2; x1 += 2u;                       // ks0 == 0
    TF_RND(13) TF_RND(15) TF_RND(26) TF_RND(6)
    x1 += ks1 + 3u;                            // x0 += ks0 is a no-op
    TF_RND(17) TF_RND(29) TF_RND(16) TF_RND(24)
    x0 += ks1; x1 += ks2 + 4u;
    TF_RND(13) TF_RND(15) TF_RND(26) TF_RND(6)
    x0 += ks2; x1 += 5u;                       // ks0 == 0
#undef TF_RND
    return x0 ^ x1;
}

// ---------------------------------------------------------------------------
// Kernel B0: split W1 (f32 [784][256]) into bf16 hi/mid/lo planes in the
// [kw][n][quarter] layout. EXACT: hi+mid+lo == w bitwise. (R21 verbatim.)
// ---------------------------------------------------------------------------
__global__ __launch_bounds__(256) void splitk_k(
        const float* __restrict__ W1, ushort* __restrict__ hiT,
        ushort* __restrict__ midT, ushort* __restrict__ loT) {
    int n = blockIdx.x;                  // 0..255
    for (int k = threadIdx.x; k < KPAD; k += 256) {
        float w = (k < IN_DIM) ? W1[k * HID + n] : 0.0f;
        uint32_t u = __float_as_uint(w);
        uint32_t hb = (u + 0x7FFFu + ((u >> 16) & 1u)) >> 16;    // RNE to bf16
        float hf = __uint_as_float(hb << 16);
        float r1 = w - hf;                                       // exact
        uint32_t u1 = __float_as_uint(r1);
        uint32_t mb = (u1 + 0x7FFFu + ((u1 >> 16) & 1u)) >> 16;  // RNE
        float mf2 = __uint_as_float(mb << 16);
        float r2 = r1 - mf2;                                     // exact
        uint32_t u2 = __float_as_uint(r2);
        uint32_t lb = (u2 + 0x7FFFu + ((u2 >> 16) & 1u)) >> 16;  // exact fit
        int kw = k >> 5, qk = (k >> 3) & 3, j = k & 7;
        size_t o = ((size_t)(kw * 256 + n) * 4 + qk) * 8 + j;
        hiT [o] = (ushort)hb;
        midT[o] = (ushort)mb;
        loT [o] = (ushort)lb;
    }
}

// ---------------------------------------------------------------------------
// Fused spikegen + GEMM + LIF scan + readout (phase-split, bit-packed A).
// Block: 80 tile rows (r = t*8 + j) x 256 cols, 512 thr = 8 waves (1M x 8N),
// wave = 80x32 = 5x2 tiles of 16x16x32. Grid 512; LDS 8.4KB -> 2 blocks/CU.
// ---------------------------------------------------------------------------
#define G_LDW   260                      // gbuf row pitch (floats)

__global__ __launch_bounds__(512, 4) void fused_gemm_k(
        const ushort* __restrict__ hiT, const ushort* __restrict__ midT,
        const ushort* __restrict__ loT, const float* __restrict__ b1,
        const float* __restrict__ x, const float* __restrict__ Wr,
        const float* __restrict__ br, float* __restrict__ out) {
    __shared__ __align__(16) char lds[8448];   // abits 8000B; gbuf 8320B
    uint32_t* abits = (uint32_t*)lds;          // word w = row*25 + kw

    const int tid = threadIdx.x;
    const int l   = tid & 63;
    const int wv  = tid >> 6;        // 0..7 = N strip (32 cols each)
    const int b0  = blockIdx.x << 3; // 8 batch rows per block

    f32x4 acc[5][2] = {};

    const int q   = l >> 4;
    const int c0  = l & 15;

    // B direct-load pointers (R21 verbatim): lane (q,c0) consumes quarter q
    // of col n; elem off = n*32 + q*8, n = wv*32 + nt*16 + c0; per-slab
    // bump +8192 elems (16KB).
    const int beoff = ((wv << 5) + c0) * 32 + (q << 3);
    const ushort* bp_hi = hiT  + beoff;
    const ushort* bp_md = midT + beoff;
    const ushort* bp_lo = loT  + beoff;

    // =======================================================================
    // Phase 1: hash all 2000 spike words via ballot. Zero barriers.
    // Lane's word this iter: wl = wv*250 + 2*it + (l>>5); bit = l&31.
    // =======================================================================
    {
        const int eL = l & 31;
        int wl = wv * 250 + (l >> 5);
#pragma unroll 1
        for (int it = 0; it < 125; ++it) {
            int row = wl / 25;                     // magic-mul
            int kw  = wl - row * 25;
            int k   = (kw << 5) + eL;
            int t   = row >> 3, j = row & 7;
            float xv = 0.0f;
            if (k < IN_DIM)                        // pad bits (k>=784) -> 0
                xv = x[(b0 + j) * IN_DIM + k];
            uint32_t ii = (uint32_t)((t << 12) + b0 + j) * (uint32_t)IN_DIM
                        + (uint32_t)k;
            uint32_t h  = tf_hash(ii);
            bool pred = (float)(h >> 9) < xv * 8388608.0f;
            unsigned long long bal = __ballot(pred);   // bit i = lane i
            if ((l & 31) == 0)
                abits[wl] = (uint32_t)((l < 32) ? bal : (bal >> 32));
            wl += 2;
        }
    }
    __syncthreads();     // the ONLY K-path barrier

    // =======================================================================
    // Phase 2: barrier-free GEMM. A read-only in LDS -> compiler pipelines
    // loads across slabs. Per slab: 6 B frags global->VGPR, 5 ds_read_b32
    // A-words (conflict-free: 16 banks x 4-way broadcast), expand, 30 MFMA.
    // =======================================================================
    const int qsh = q << 3;
#pragma unroll 1
    for (int kw = 0; kw < KWORDS; ++kw) {
        bf16x8 bfr[3][2];
#pragma unroll
        for (int nt = 0; nt < 2; ++nt) {
            bfr[0][nt] = *(const bf16x8*)(bp_hi + nt * 512);
            bfr[1][nt] = *(const bf16x8*)(bp_md + nt * 512);
            bfr[2][nt] = *(const bf16x8*)(bp_lo + nt * 512);
        }
        bp_hi += 8192; bp_md += 8192; bp_lo += 8192;

        bf16x8 af[5];
#pragma unroll
        for (int mt = 0; mt < 5; ++mt) {
            uint32_t wrd = abits[(mt * 16 + c0) * 25 + kw];
            uint32_t byt = (wrd >> qsh) & 0xFFu;   // logical quarter q
            u32x4 v;                               // bit 2d -> low bf16 of v[d]
            v.x = ((byt & 1u)   ? 0x3F80u : 0u) | ((byt & 2u)   ? 0x3F800000u : 0u);
            v.y = ((byt & 4u)   ? 0x3F80u : 0u) | ((byt & 8u)   ? 0x3F800000u : 0u);
            v.z = ((byt & 16u)  ? 0x3F80u : 0u) | ((byt & 32u)  ? 0x3F800000u : 0u);
            v.w = ((byt & 64u)  ? 0x3F80u : 0u) | ((byt & 128u) ? 0x3F800000u : 0u);
            af[mt] = *(bf16x8*)&v;
        }

#pragma unroll
        for (int nt = 0; nt < 2; ++nt) {
#pragma unroll
            for (int mt = 0; mt < 5; ++mt) {
                acc[mt][nt] = __builtin_amdgcn_mfma_f32_16x16x32_bf16(af[mt], bfr[0][nt], acc[mt][nt], 0, 0, 0);
                acc[mt][nt] = __builtin_amdgcn_mfma_f32_16x16x32_bf16(af[mt], bfr[1][nt], acc[mt][nt], 0, 0, 0);
                acc[mt][nt] = __builtin_amdgcn_mfma_f32_16x16x32_bf16(af[mt], bfr[2][nt], acc[mt][nt], 0, 0, 0);
            }
        }
    }

    // =======================================================================
    // Epilogue (R22 verbatim): LIF scan via lane-pair exchange + readout.
    // acc[mt][nt][rr] = I(t = 2*mt + (q>>1), j = (q&1)*4+rr,
    // col = wv*32 + nt*16 + c0).  Partner lane = l ^ 32.
    // =======================================================================
    float b1v[2];
#pragma unroll
    for (int nt = 0; nt < 2; ++nt)
        b1v[nt] = b1[(wv << 5) + (nt << 4) + c0];

    float av[5][2][4];
#pragma unroll
    for (int mt = 0; mt < 5; ++mt)
#pragma unroll
        for (int nt = 0; nt < 2; ++nt)
#pragma unroll
            for (int rr = 0; rr < 4; ++rr)
                av[mt][nt][rr] = acc[mt][nt][rr] + b1v[nt];

    const int qh = q >> 1;               // 0: holds even t; 1: holds odd t
    float g[2][4];
#pragma unroll
    for (int nt = 0; nt < 2; ++nt) {
#pragma unroll
        for (int rr = 0; rr < 4; ++rr) {
            float v = 0.f, ga = 0.f, wt = 0.0009765625f;   // 2^-10
#pragma unroll
            for (int m = 0; m < 5; ++m) {
                float pv = __shfl_xor(av[m][nt][rr], 32);  // partner's value
                float Ie = qh ? pv : av[m][nt][rr];        // t = 2m
                float Io = qh ? av[m][nt][rr] : pv;        // t = 2m+1
                v = v + (Ie - v) * 0.5f;
                if (v >= 1.0f) { ga += wt; v = 0.f; }
                wt += wt;
                v = v + (Io - v) * 0.5f;
                if (v >= 1.0f) { ga += wt; v = 0.f; }
                wt += wt;
            }
            g[nt][rr] = ga;
        }
    }

    __syncthreads();                     // all waves done reading abits
    float* gbuf = (float*)lds;           // [8][G_LDW] overlays abits
    if (l < 32) {                        // qh==0 lanes hold canonical g
#pragma unroll
        for (int nt = 0; nt < 2; ++nt)
#pragma unroll
            for (int rr = 0; rr < 4; ++rr) {
                int jj  = ((q & 1) << 2) + rr;
                int col = (wv << 5) + (nt << 4) + c0;
                gbuf[jj * G_LDW + col] = g[nt][rr];
            }
    }
    __syncthreads();

    {   // readout: wave wv -> batch row b0+wv; identical fmaf chain
        const int c = l;
        if (c < NCLS) {
            const float* gb = &gbuf[wv * G_LDW];
            float a = 0.f;
            for (int h4 = 0; h4 < 64; ++h4) {
                float w0 = Wr[((h4 << 2) + 0) * NCLS + c];
                float w1 = Wr[((h4 << 2) + 1) * NCLS + c];
                float w2 = Wr[((h4 << 2) + 2) * NCLS + c];
                float w3 = Wr[((h4 << 2) + 3) * NCLS + c];
                float4 gg = *(const float4*)&gb[h4 << 2];
                a = fmaf(gg.x, w0, a);
                a = fmaf(gg.y, w1, a);
                a = fmaf(gg.z, w2, a);
                a = fmaf(gg.w, w3, a);
            }
            out[(b0 + wv) * NCLS + c] = a + br[c] * 0.9990234375f;
        }
    }
}

extern "C" void kernel_launch(void* const* d_in, const int* in_sizes, int n_in,
                              void* d_out, int out_size, void* d_ws, size_t ws_size,
                              hipStream_t stream) {
    const float* x  = (const float*)d_in[0];
    const float* W1 = (const float*)d_in[1];
    const float* b1 = (const float*)d_in[2];
    const float* Wr = (const float*)d_in[3];
    const float* br = (const float*)d_in[4];
    float* out = (float*)d_out;

    ushort* w1hi  = (ushort*)((char*)d_ws + WS_W1HI_OFF);
    ushort* w1md  = (ushort*)((char*)d_ws + WS_W1MD_OFF);
    ushort* w1lo  = (ushort*)((char*)d_ws + WS_W1LO_OFF);

    splitk_k<<<HID, 256, 0, stream>>>(W1, w1hi, w1md, w1lo);
    fused_gemm_k<<<BATCH / 8, 512, 0, stream>>>(w1hi, w1md, w1lo, b1, x,
                                                Wr, br, out);
}

// Round 13
// 169.619 us; speedup vs baseline: 1.3288x; 1.3288x over previous
//
#include <hip/hip_runtime.h>
#include <stdint.h>

// ---------------------------------------------------------------------------
// SNN EMNIST forward: T=10, B=4096, IN=784, HID=256, NCLS=47
// R24: combine the two proven levers that have never been combined:
//  (a) R13-spikegen hash codegen (word-per-thread, 32 hashes per address
//      setup, float4 x loads) = 56us chip-wide issue -- the most efficient
//      form ever measured (R23's per-bit ballot form was 137us);
//  (b) R23's barrier-free phase split at 4 waves/SIMD = 75.6% VALUBusy --
//      the highest busy ever measured (per-slab-barrier forms: 53-61%).
// Phase 1: 2000 spike words/block (w = row*25+kw); thread handles
// w = tid + s*512 (s=0..3; s=3 valid iff tid<464): one div per 32 hashes,
// R13's exact group/compare/bit-OR expression, ds_write_b32 to abits[w]
// (2-way bank alias = free). Zero barriers.
// Phase 2 + epilogue: R23 VERBATIM (0 bank conflicts measured; expansion
// verified). Same bits -> same fragments -> same MFMA order -> I bitwise
// identical -> absmax stays 4.882812e-4. splitk unchanged.
// ---------------------------------------------------------------------------

#define T_STEPS 10
#define BATCH   4096
#define IN_DIM  784
#define HID     256
#define NCLS    47
#define KWORDS  25                       // ceil(784/32)
#define KPAD    800                      // 25*32

// d_ws layout (bytes):
//   [46039040, ...)  W1{hi,mid,lo} planes: bf16, 409600 B each,
//                    layout [kw][n][quarter] (R21): elem off for (k,n) =
//                    ((kw*256+n)*4 + (k>>3)&3)*8 + (k&7),  kw = k>>5.
#define WS_W1HI_OFF 46039040u
#define WS_W1MD_OFF (46039040u + 409600u)
#define WS_W1LO_OFF (46039040u + 819200u)

typedef __attribute__((ext_vector_type(8))) short    bf16x8;
typedef __attribute__((ext_vector_type(4))) float    f32x4;
typedef __attribute__((ext_vector_type(4))) uint32_t u32x4;

__device__ __forceinline__ uint32_t rotl32(uint32_t x, uint32_t r) {
    return __builtin_amdgcn_alignbit(x, x, 32u - r);
}

// JAX threefry2x32, key=(0,42), partitionable scheme: out = o0^o1, x0=0, x1=i.
__device__ __forceinline__ uint32_t tf_hash(uint32_t lo) {
    const uint32_t ks1 = 42u;
    const uint32_t ks2 = 0x1BD11BDAu ^ 42u;
    uint32_t x0 = 0u;
    uint32_t x1 = lo + ks1;
#define TF_RND(r) { x0 += x1; x1 = rotl32(x1, r); x1 ^= x0; }
    TF_RND(13) TF_RND(15) TF_RND(26) TF_RND(6)
    x0 += ks1; x1 += ks2 + 1u;
    TF_RND(17) TF_RND(29) TF_RND(16) TF_RND(24)
    x0 += ks2; x1 += 2u;                       // ks0 == 0
    TF_RND(13) TF_RND(15) TF_RND(26) TF_RND(6)
    x1 += ks1 + 3u;                            // x0 += ks0 is a no-op
    TF_RND(17) TF_RND(29) TF_RND(16) TF_RND(24)
    x0 += ks1; x1 += ks2 + 4u;
    TF_RND(13) TF_RND(15) TF_RND(26) TF_RND(6)
    x0 += ks2; x1 += 5u;                       // ks0 == 0
#undef TF_RND
    return x0 ^ x1;
}

// ---------------------------------------------------------------------------
// Kernel B0: split W1 (f32 [784][256]) into bf16 hi/mid/lo planes in the
// [kw][n][quarter] layout. EXACT: hi+mid+lo == w bitwise. (R21 verbatim.)
// ---------------------------------------------------------------------------
__global__ __launch_bounds__(256) void splitk_k(
        const float* __restrict__ W1, ushort* __restrict__ hiT,
        ushort* __restrict__ midT, ushort* __restrict__ loT) {
    int n = blockIdx.x;                  // 0..255
    for (int k = threadIdx.x; k < KPAD; k += 256) {
        float w = (k < IN_DIM) ? W1[k * HID + n] : 0.0f;
        uint32_t u = __float_as_uint(w);
        uint32_t hb = (u + 0x7FFFu + ((u >> 16) & 1u)) >> 16;    // RNE to bf16
        float hf = __uint_as_float(hb << 16);
        float r1 = w - hf;                                       // exact
        uint32_t u1 = __float_as_uint(r1);
        uint32_t mb = (u1 + 0x7FFFu + ((u1 >> 16) & 1u)) >> 16;  // RNE
        float mf2 = __uint_as_float(mb << 16);
        float r2 = r1 - mf2;                                     // exact
        uint32_t u2 = __float_as_uint(r2);
        uint32_t lb = (u2 + 0x7FFFu + ((u2 >> 16) & 1u)) >> 16;  // exact fit
        int kw = k >> 5, qk = (k >> 3) & 3, j = k & 7;
        size_t o = ((size_t)(kw * 256 + n) * 4 + qk) * 8 + j;
        hiT [o] = (ushort)hb;
        midT[o] = (ushort)mb;
        loT [o] = (ushort)lb;
    }
}

// ---------------------------------------------------------------------------
// Fused spikegen + GEMM + LIF scan + readout (phase-split, bit-packed A,
// R13-codegen hash). Block: 80 tile rows (r = t*8 + j) x 256 cols, 512 thr
// = 8 waves (1M x 8N), wave = 80x32 = 5x2 tiles of 16x16x32. Grid 512;
// LDS 8.4KB -> multiple blocks/CU, blocks drift across phases.
// ---------------------------------------------------------------------------
#define G_LDW   260                      // gbuf row pitch (floats)

__global__ __launch_bounds__(512, 4) void fused_gemm_k(
        const ushort* __restrict__ hiT, const ushort* __restrict__ midT,
        const ushort* __restrict__ loT, const float* __restrict__ b1,
        const float* __restrict__ x, const float* __restrict__ Wr,
        const float* __restrict__ br, float* __restrict__ out) {
    __shared__ __align__(16) char lds[8448];   // abits 8000B; gbuf 8320B
    uint32_t* abits = (uint32_t*)lds;          // word w = row*25 + kw

    const int tid = threadIdx.x;
    const int l   = tid & 63;
    const int wv  = tid >> 6;        // 0..7 = N strip (32 cols each)
    const int b0  = blockIdx.x << 3; // 8 batch rows per block

    f32x4 acc[5][2] = {};

    const int q   = l >> 4;
    const int c0  = l & 15;

    // B direct-load pointers (R21 verbatim): lane (q,c0) consumes quarter q
    // of col n; elem off = n*32 + q*8, n = wv*32 + nt*16 + c0; per-slab
    // bump +8192 elems (16KB).
    const int beoff = ((wv << 5) + c0) * 32 + (q << 3);
    const ushort* bp_hi = hiT  + beoff;
    const ushort* bp_md = midT + beoff;
    const ushort* bp_lo = loT  + beoff;

    // =======================================================================
    // Phase 1: hash all 2000 spike words, R13-spikegen codegen (one address
    // setup per 32 hashes, float4 x loads, bit-OR pack, one ds_write_b32).
    // Zero barriers. s=0..2 fully valid; s=3 valid iff tid < 464.
    // =======================================================================
#pragma unroll
    for (int s = 0; s < 4; ++s) {
        int w = tid + (s << 9);
        if (w < 2000) {
            int row = w / 25;                      // magic-mul
            int kw  = w - row * 25;
            int j   = row & 7, t = row >> 3;
            int k0  = kw << 5;
            const float* xp = x + (b0 + j) * IN_DIM + k0;
            uint32_t ib = (uint32_t)(t * BATCH + b0 + j) * (uint32_t)IN_DIM
                        + (uint32_t)k0;
            uint32_t wbits = 0u;
#pragma unroll
            for (int g = 0; g < 4; ++g) {
                if (!(kw == KWORDS - 1 && g >= 2)) {   // tail: k>=784 -> 0
                    float4 xa = *(const float4*)(xp + (g << 3));
                    float4 xb = *(const float4*)(xp + (g << 3) + 4);
                    uint32_t base = ib + (uint32_t)(g << 3);
                    uint32_t bits = 0u;
                    bits |= ((float)(tf_hash(base + 0u) >> 9) < xa.x * 8388608.0f) ? 1u   : 0u;
                    bits |= ((float)(tf_hash(base + 1u) >> 9) < xa.y * 8388608.0f) ? 2u   : 0u;
                    bits |= ((float)(tf_hash(base + 2u) >> 9) < xa.z * 8388608.0f) ? 4u   : 0u;
                    bits |= ((float)(tf_hash(base + 3u) >> 9) < xa.w * 8388608.0f) ? 8u   : 0u;
                    bits |= ((float)(tf_hash(base + 4u) >> 9) < xb.x * 8388608.0f) ? 16u  : 0u;
                    bits |= ((float)(tf_hash(base + 5u) >> 9) < xb.y * 8388608.0f) ? 32u  : 0u;
                    bits |= ((float)(tf_hash(base + 6u) >> 9) < xb.z * 8388608.0f) ? 64u  : 0u;
                    bits |= ((float)(tf_hash(base + 7u) >> 9) < xb.w * 8388608.0f) ? 128u : 0u;
                    wbits |= bits << (g << 3);
                }
            }
            abits[w] = wbits;
        }
    }
    __syncthreads();     // the ONLY K-path barrier

    // =======================================================================
    // Phase 2 (R23 verbatim): barrier-free GEMM. Per slab: 6 B frags
    // global->VGPR, 5 ds_read_b32 A-words (16 banks x 4-way broadcast =
    // conflict-free), byte-q expand, 30 MFMA.
    // =======================================================================
    const int qsh = q << 3;
#pragma unroll 1
    for (int kw = 0; kw < KWORDS; ++kw) {
        bf16x8 bfr[3][2];
#pragma unroll
        for (int nt = 0; nt < 2; ++nt) {
            bfr[0][nt] = *(const bf16x8*)(bp_hi + nt * 512);
            bfr[1][nt] = *(const bf16x8*)(bp_md + nt * 512);
            bfr[2][nt] = *(const bf16x8*)(bp_lo + nt * 512);
        }
        bp_hi += 8192; bp_md += 8192; bp_lo += 8192;

        bf16x8 af[5];
#pragma unroll
        for (int mt = 0; mt < 5; ++mt) {
            uint32_t wrd = abits[(mt * 16 + c0) * 25 + kw];
            uint32_t byt = (wrd >> qsh) & 0xFFu;   // logical quarter q
            u32x4 v;                               // bit 2d -> low bf16 of v[d]
            v.x = ((byt & 1u)   ? 0x3F80u : 0u) | ((byt & 2u)   ? 0x3F800000u : 0u);
            v.y = ((byt & 4u)   ? 0x3F80u : 0u) | ((byt & 8u)   ? 0x3F800000u : 0u);
            v.z = ((byt & 16u)  ? 0x3F80u : 0u) | ((byt & 32u)  ? 0x3F800000u : 0u);
            v.w = ((byt & 64u)  ? 0x3F80u : 0u) | ((byt & 128u) ? 0x3F800000u : 0u);
            af[mt] = *(bf16x8*)&v;
        }

#pragma unroll
        for (int nt = 0; nt < 2; ++nt) {
#pragma unroll
            for (int mt = 0; mt < 5; ++mt) {
                acc[mt][nt] = __builtin_amdgcn_mfma_f32_16x16x32_bf16(af[mt], bfr[0][nt], acc[mt][nt], 0, 0, 0);
                acc[mt][nt] = __builtin_amdgcn_mfma_f32_16x16x32_bf16(af[mt], bfr[1][nt], acc[mt][nt], 0, 0, 0);
                acc[mt][nt] = __builtin_amdgcn_mfma_f32_16x16x32_bf16(af[mt], bfr[2][nt], acc[mt][nt], 0, 0, 0);
            }
        }
    }

    // =======================================================================
    // Epilogue (R23 verbatim): LIF scan via lane-pair exchange + readout.
    // acc[mt][nt][rr] = I(t = 2*mt + (q>>1), j = (q&1)*4+rr,
    // col = wv*32 + nt*16 + c0).  Partner lane = l ^ 32.
    // =======================================================================
    float b1v[2];
#pragma unroll
    for (int nt = 0; nt < 2; ++nt)
        b1v[nt] = b1[(wv << 5) + (nt << 4) + c0];

    float av[5][2][4];
#pragma unroll
    for (int mt = 0; mt < 5; ++mt)
#pragma unroll
        for (int nt = 0; nt < 2; ++nt)
#pragma unroll
            for (int rr = 0; rr < 4; ++rr)
                av[mt][nt][rr] = acc[mt][nt][rr] + b1v[nt];

    const int qh = q >> 1;               // 0: holds even t; 1: holds odd t
    float g[2][4];
#pragma unroll
    for (int nt = 0; nt < 2; ++nt) {
#pragma unroll
        for (int rr = 0; rr < 4; ++rr) {
            float v = 0.f, ga = 0.f, wt = 0.0009765625f;   // 2^-10
#pragma unroll
            for (int m = 0; m < 5; ++m) {
                float pv = __shfl_xor(av[m][nt][rr], 32);  // partner's value
                float Ie = qh ? pv : av[m][nt][rr];        // t = 2m
                float Io = qh ? av[m][nt][rr] : pv;        // t = 2m+1
                v = v + (Ie - v) * 0.5f;
                if (v >= 1.0f) { ga += wt; v = 0.f; }
                wt += wt;
                v = v + (Io - v) * 0.5f;
                if (v >= 1.0f) { ga += wt; v = 0.f; }
                wt += wt;
            }
            g[nt][rr] = ga;
        }
    }

    __syncthreads();                     // all waves done reading abits
    float* gbuf = (float*)lds;           // [8][G_LDW] overlays abits
    if (l < 32) {                        // qh==0 lanes hold canonical g
#pragma unroll
        for (int nt = 0; nt < 2; ++nt)
#pragma unroll
            for (int rr = 0; rr < 4; ++rr) {
                int jj  = ((q & 1) << 2) + rr;
                int col = (wv << 5) + (nt << 4) + c0;
                gbuf[jj * G_LDW + col] = g[nt][rr];
            }
    }
    __syncthreads();

    {   // readout: wave wv -> batch row b0+wv; identical fmaf chain
        const int c = l;
        if (c < NCLS) {
            const float* gb = &gbuf[wv * G_LDW];
            float a = 0.f;
            for (int h4 = 0; h4 < 64; ++h4) {
                float w0 = Wr[((h4 << 2) + 0) * NCLS + c];
                float w1 = Wr[((h4 << 2) + 1) * NCLS + c];
                float w2 = Wr[((h4 << 2) + 2) * NCLS + c];
                float w3 = Wr[((h4 << 2) + 3) * NCLS + c];
                float4 gg = *(const float4*)&gb[h4 << 2];
                a = fmaf(gg.x, w0, a);
                a = fmaf(gg.y, w1, a);
                a = fmaf(gg.z, w2, a);
                a = fmaf(gg.w, w3, a);
            }
            out[(b0 + wv) * NCLS + c] = a + br[c] * 0.9990234375f;
        }
    }
}

extern "C" void kernel_launch(void* const* d_in, const int* in_sizes, int n_in,
                              void* d_out, int out_size, void* d_ws, size_t ws_size,
                              hipStream_t stream) {
    const float* x  = (const float*)d_in[0];
    const float* W1 = (const float*)d_in[1];
    const float* b1 = (const float*)d_in[2];
    const float* Wr = (const float*)d_in[3];
    const float* br = (const float*)d_in[4];
    float* out = (float*)d_out;

    ushort* w1hi  = (ushort*)((char*)d_ws + WS_W1HI_OFF);
    ushort* w1md  = (ushort*)((char*)d_ws + WS_W1MD_OFF);
    ushort* w1lo  = (ushort*)((char*)d_ws + WS_W1LO_OFF);

    splitk_k<<<HID, 256, 0, stream>>>(W1, w1hi, w1md, w1lo);
    fused_gemm_k<<<BATCH / 8, 512, 0, stream>>>(w1hi, w1md, w1lo, b1, x,
                                                Wr, br, out);
}